// Round 13
// baseline (118.751 us; speedup 1.0000x reference)
//
#include <hip/hip_runtime.h>
#include <hip/hip_bf16.h>
#include <math.h>

#define BB   4
#define CCH  256
#define KK   8
#define NPIX 16384
#define TILE 64
#define NBLK 256           // blocks per batch = NPIX/TILE
#define TEMP_INV 1.25f     // 1/0.8
#define EPSF 1e-6f

__device__ __forceinline__ float bf_lo(unsigned int u) { return __uint_as_float(u << 16); }
__device__ __forceinline__ float bf_hi(unsigned int u) { return __uint_as_float(u & 0xffff0000u); }
__device__ __forceinline__ unsigned short bfbits(float f) {
    __hip_bfloat16 h = __float2bfloat16(f);
    return *reinterpret_cast<unsigned short*>(&h);
}
__device__ __forceinline__ float us2f(unsigned short u) {
    return __uint_as_float((unsigned int)u << 16);
}

// ---------------------------------------------------------------------------
// Pass kernel. r11 memory behavior preserved EXACTLY (lane=pixel 256B wave
// loads, per-c-uniform fb swizzle, s_load proto); the one change (r13): for
// MODE 1/2 the cross staging is bf16 in a half-size buffer with 2-group
// accumulation -> LDS 38.2KB -> 4 blocks/CU -> grid 1024 = ONE scheduling
// round (r11's 52.6KB = 3/CU = 768 slots = 2 uneven rounds).
// MODE 0 keeps the r11 fp32 staging verbatim (3/CU; isolates bf16 risk).
// [r12 lessons: 8px-wide column loads = sector scatter, cgrp-dependent store
//  swizzle = 4-way conflicts. r4/r10: no bf16 global feats cache. r7/r9: no
//  cross-block sync. r5: no 256-deep serial load chains.]
// fb tile swizzle: word wp = (p>>1) ^ (S(c)<<1), S = (c&15)^((c>>4)&3) --
// per-iteration-constant on the store side (conflict-free), decorrelates the
// 4 same-(c&15) lanes on the phase-2 read side.
// ---------------------------------------------------------------------------
template<int MODE>
__global__ __launch_bounds__(512, (MODE == 0) ? 6 : 8)
void skm_pass(const float* __restrict__ feats,
              const float* __restrict__ seed_w,
              const float* __restrict__ seed_b,
              const float* __restrict__ proto_t,   // [b][256][8]
              const float* __restrict__ psq_part,  // [b][8][8]
              float* __restrict__ fsq,
              float* __restrict__ part_num,
              float* __restrict__ part_den,
              float* __restrict__ logits_out,
              float* __restrict__ probs_out)
{
    __shared__ unsigned int fb_s[CCH][32];   // 32 KB: bf16 feats tile, swizzled
    __shared__ float w_s[KK][68];            // 2.1 KB (rows 16B-aligned)
    constexpr int XBYTES = (MODE == 0) ? (8 * KK * 66 * 4 + 8 * TILE * 4)  // cross_f + fs
                                       : (4 * KK * 66 * 2);                // cross_h (bf16)
    __shared__ __align__(16) unsigned char xmem[XBYTES];
    float (*cross_f)[KK][66] = (float (*)[KK][66])xmem;                    // MODE 0
    float (*aux)[TILE] = (float (*)[TILE])(xmem + 8 * KK * 66 * 4);        // MODE 0 fs
    unsigned short (*cross_h)[KK][66] = (unsigned short (*)[KK][66])xmem;  // MODE 1/2
    float (*lgst)[66] = (float (*)[66])xmem;                               // MODE 2 lg (overlay)

    const int t   = threadIdx.x;
    const int bid = blockIdx.x;
    const int b   = bid >> 8;
    const int blk = bid & 255;
    const int n0  = blk * TILE;

    // ---- phase 1: cross[k][p]; 8 waves = 8 channel-groups of 32 (r11) ----
    const int p  = t & 63;                               // pixel (lane)
    const int g  = t >> 6;                               // wave = channel group
    const int c0 = __builtin_amdgcn_readfirstlane(g) * 32;
    const float* fcol = feats + (size_t)b * CCH * NPIX + (size_t)c0 * NPIX + n0 + p;
    const float* pt   = proto_t + (size_t)b * CCH * KK + (size_t)c0 * KK;

    float cr[KK];
    #pragma unroll
    for (int k = 0; k < KK; ++k) cr[k] = 0.f;
    float fs = 0.f;

    #pragma unroll 8
    for (int cc = 0; cc < 32; ++cc) {
        const float f = fcol[(size_t)cc * NPIX];         // coalesced 256B/wave
        if (MODE == 0) fs = fmaf(f, f, fs);
        const int c  = c0 + cc;
        const int wp = (p >> 1) ^ ((((c & 15) ^ ((c >> 4) & 3))) << 1);   // per-c const
        ((unsigned short*)fb_s)[(c << 6) + (wp << 1) + (p & 1)] = bfbits(f);
        if (MODE == 0) {
            #pragma unroll
            for (int k = 0; k < KK; ++k)
                cr[k] = fmaf(seed_w[k * CCH + c], f, cr[k]);   // uniform -> s_load
        } else {
            const float* pr = pt + cc * KK;              // uniform -> s_load x8
            #pragma unroll
            for (int k = 0; k < KK; ++k)
                cr[k] = fmaf(pr[k], f, cr[k]);
        }
    }

    // ---- cross staging ----
    if (MODE == 0) {
        #pragma unroll
        for (int k = 0; k < KK; ++k) cross_f[g][k][p] = cr[k];
        aux[g][p] = fs;
        __syncthreads();
    } else {
        if (g < 4) {
            #pragma unroll
            for (int k = 0; k < KK; ++k) cross_h[g][k][p] = bfbits(cr[k]);
        }
        __syncthreads();
        if (g >= 4) {
            #pragma unroll
            for (int k = 0; k < KK; ++k)
                cross_h[g - 4][k][p] = bfbits(us2f(cross_h[g - 4][k][p]) + cr[k]);
        }
        __syncthreads();
    }

    // ---- softmax over k: thread = (pixel pp, cluster k), shuffle in octet ----
    {
        const int pp = t >> 3, k = t & 7;
        float lg = 0.f;
        if (MODE == 0) {
            #pragma unroll
            for (int gg = 0; gg < 8; ++gg) lg += cross_f[gg][k][pp];
            lg += seed_b[k];
            if (k == 0) {
                float fv = 0.f;
                #pragma unroll
                for (int gg = 0; gg < 8; ++gg) fv += aux[gg][pp];
                fsq[b * NPIX + n0 + pp] = fv;
            }
        } else {
            #pragma unroll
            for (int gg = 0; gg < 4; ++gg) lg += us2f(cross_h[gg][k][pp]);
            const float4 q0 = ((const float4*)psq_part)[(b * KK + k) * 2];
            const float4 q1 = ((const float4*)psq_part)[(b * KK + k) * 2 + 1];
            const float pk = ((q0.x + q0.y) + (q0.z + q0.w))
                           + ((q1.x + q1.y) + (q1.z + q1.w));
            if (MODE == 2) {
                const float fv = fsq[b * NPIX + n0 + pp];
                lg = (2.f * lg - fv - pk) * TEMP_INV;    // true -dist/TEMP (output)
            } else {
                lg = fmaf(2.f * TEMP_INV, lg, -TEMP_INV * pk);  // f_sq dropped (invariant)
            }
        }
        float m = lg;
        m = fmaxf(m, __shfl_xor(m, 1, 64));
        m = fmaxf(m, __shfl_xor(m, 2, 64));
        m = fmaxf(m, __shfl_xor(m, 4, 64));
        const float e = expf(lg - m);
        float ssum = e;
        ssum += __shfl_xor(ssum, 1, 64);
        ssum += __shfl_xor(ssum, 2, 64);
        ssum += __shfl_xor(ssum, 4, 64);
        const float wv = e / ssum;
        if (MODE == 2) {
            __syncthreads();            // cross_h reads done -> safe to overlay lg
            lgst[k][pp] = lg;
        }
        w_s[k][pp] = wv;
    }
    __syncthreads();

    // ---- MODE 2: coalesced logits/probs writes ----
    if (MODE == 2) {
        const int k2 = t >> 6, p2 = t & 63;
        logits_out[((size_t)b * KK + k2) * NPIX + n0 + p2] = lgst[k2][p2];
        probs_out [((size_t)b * KK + k2) * NPIX + n0 + p2] = w_s[k2][p2];
    }

    // ---- per-block denominator partials (threads 0..255) ----
    if (t < 256) {
        const int kk = t >> 5, ll = t & 31;
        float s = w_s[kk][2 * ll] + w_s[kk][2 * ll + 1];
        s += __shfl_xor(s, 16, 64);
        s += __shfl_xor(s, 8, 64);
        s += __shfl_xor(s, 4, 64);
        s += __shfl_xor(s, 2, 64);
        s += __shfl_xor(s, 1, 64);
        if (ll == 0) part_den[(b * NBLK + blk) * KK + kk] = s;
    }

    // ---- phase 2: num[k][c] from bf16 LDS tile; thread (c, kh) owns the
    //      FULL 64-px row for 4 k's -> direct part_num write (no staging) ----
    {
        const int c  = t & 255, kh = t >> 8;             // kh: k 0-3 / 4-7
        const int sw = (c & 15) ^ ((c >> 4) & 3);        // uint2-index swizzle
        const uint2* row2 = (const uint2*)fb_s[c];
        const int kb = kh * 4;
        float acc[4];
        #pragma unroll
        for (int kk2 = 0; kk2 < 4; ++kk2) acc[kk2] = 0.f;
        #pragma unroll
        for (int j = 0; j < 16; ++j) {
            const uint2 u = row2[j ^ sw];
            const float f0 = bf_lo(u.x), f1 = bf_hi(u.x);
            const float f2 = bf_lo(u.y), f3 = bf_hi(u.y);
            const int pxj = 4 * j;
            #pragma unroll
            for (int kk2 = 0; kk2 < 4; ++kk2) {
                const float4 w4 = *(const float4*)&w_s[kb + kk2][pxj];  // bcast b128
                acc[kk2] = fmaf(f3, w4.w, fmaf(f2, w4.z,
                           fmaf(f1, w4.y, fmaf(f0, w4.x, acc[kk2]))));
            }
        }
        #pragma unroll
        for (int kk2 = 0; kk2 < 4; ++kk2)
            part_num[(((size_t)b * NBLK + blk) * KK + (kb + kk2)) * CCH + c] = acc[kk2];
    }
}

// ---------------------------------------------------------------------------
// Reduce (r11-proven, 512 threads, 16-way j-split): 256 blocks = 32 (b,k) x 8
// channel-chunks; writes proto_t (+proto_out) AND psq_part chunk.
// FINAL=true: blocks >= 256 do the bilinear x4 upsample (512-wide).
// ---------------------------------------------------------------------------
template<bool FINAL>
__global__ __launch_bounds__(512)
void skm_reduce(const float* __restrict__ part_num,
                const float* __restrict__ part_den,
                float* __restrict__ proto_t,
                float* __restrict__ psq_part,
                float* __restrict__ proto_out,
                const float* __restrict__ probs_ws,
                float* __restrict__ probs_full)
{
    const int bid = blockIdx.x;
    if (FINAL && bid >= 256) {
        // ---- upsample role: half-pixel bilinear x4, edge clamp ----
        const int gid = (bid - 256) * 512 + threadIdx.x;   // 0..2097151
        const int jb = gid & 127;
        const int i  = (gid >> 7) & 511;
        const int bk = gid >> 16;
        const float* src = probs_ws + (size_t)bk * NPIX;
        const float y   = i * 0.25f - 0.375f;
        const float y0f = floorf(y);
        const float fy  = y - y0f;
        const int   y0  = (int)y0f;
        const int ya = min(max(y0, 0), 127);
        const int yb = min(max(y0 + 1, 0), 127);
        const int xm = max(jb - 1, 0);
        const int xp = min(jb + 1, 127);
        const float* r0 = src + ya * 128;
        const float* r1 = src + yb * 128;
        const float wy0 = 1.f - fy;
        const float am = r0[xm] * wy0 + r1[xm] * fy;
        const float ac = r0[jb] * wy0 + r1[jb] * fy;
        const float ap = r0[xp] * wy0 + r1[xp] * fy;
        float4 o;
        o.x = 0.375f * am + 0.625f * ac;
        o.y = 0.125f * am + 0.875f * ac;
        o.z = 0.875f * ac + 0.125f * ap;
        o.w = 0.625f * ac + 0.375f * ap;
        ((float4*)probs_full)[gid] = o;
        return;
    }

    const int cq = bid & 7;
    const int bk = bid >> 3;             // 0..31
    const int b = bk >> 3, k = bk & 7;
    const int t = threadIdx.x;

    __shared__ float red[16][32];
    __shared__ float den_s[4];

    // denominator: threads 0-255 read 256 block-partials, per-wave shuffle tree
    float dv = (t < 256) ? part_den[(b * NBLK + t) * KK + k] : 0.f;
    dv += __shfl_xor(dv, 32, 64);
    dv += __shfl_xor(dv, 16, 64);
    dv += __shfl_xor(dv, 8, 64);
    dv += __shfl_xor(dv, 4, 64);
    dv += __shfl_xor(dv, 2, 64);
    dv += __shfl_xor(dv, 1, 64);
    if (t < 256 && (t & 63) == 0) den_s[t >> 6] = dv;

    // numerator: 16-way j-split over this role's 32 channels
    const int jj = t >> 5, cl = t & 31;
    const int c = cq * 32 + cl;
    float s = 0.f;
    #pragma unroll 4
    for (int j = 0; j < 16; ++j)
        s += part_num[(((size_t)b * NBLK + jj * 16 + j) * KK + k) * CCH + c];
    red[jj][cl] = s;
    __syncthreads();

    if (t < 32) {
        const float den = den_s[0] + den_s[1] + den_s[2] + den_s[3] + EPSF;
        float pv = 0.f;
        #pragma unroll
        for (int j2 = 0; j2 < 16; ++j2) pv += red[j2][t];
        pv /= den;
        const int c2 = cq * 32 + t;
        proto_t[((size_t)b * CCH + c2) * KK + k] = pv;
        if (proto_out) proto_out[(b * KK + k) * CCH + c2] = pv;
        float q = pv * pv;                               // psq chunk partial
        q += __shfl_xor(q, 16, 64);
        q += __shfl_xor(q, 8, 64);
        q += __shfl_xor(q, 4, 64);
        q += __shfl_xor(q, 2, 64);
        q += __shfl_xor(q, 1, 64);
        if (t == 0) psq_part[(b * KK + k) * 8 + cq] = q;
    }
}

// ---------------------------------------------------------------------------
extern "C" void kernel_launch(void* const* d_in, const int* in_sizes, int n_in,
                              void* d_out, int out_size, void* d_ws, size_t ws_size,
                              hipStream_t stream)
{
    const float* feats  = (const float*)d_in[0];   // [4][256][16384]
    const float* seed_w = (const float*)d_in[1];   // [16][256] (first 8 rows)
    const float* seed_b = (const float*)d_in[2];   // [16]

    float* out        = (float*)d_out;
    float* probs_full = out;                        // 4*8*512*512 = 8388608
    float* proto_out  = out + 8388608;              // 4*8*256     = 8192
    float* logits_out = out + 8388608 + 8192;       // 4*8*128*128 = 524288

    float* ws       = (float*)d_ws;
    float* fsq      = ws;                           // 65536
    float* part_den = ws + 65536;                   // 4*256*8 = 8192
    float* proto_t  = part_den + 8192;              // 8192
    float* psq_part = proto_t + 8192;               // 256
    float* probs_ws = psq_part + 256;               // 524288
    float* part_num = probs_ws + 524288;            // 2097152 (~10.7 MB total)

    const dim3 pg(BB * NBLK), pb(512);
    const dim3 rg(256), rb(512);

    // seed pass + initial proto
    skm_pass<0><<<pg, pb, 0, stream>>>(feats, seed_w, seed_b, proto_t, psq_part,
                                       fsq, part_num, part_den, nullptr, nullptr);
    skm_reduce<false><<<rg, rb, 0, stream>>>(part_num, part_den, proto_t, psq_part,
                                             nullptr, probs_ws, probs_full);
    // cluster iterations 1,2
    skm_pass<1><<<pg, pb, 0, stream>>>(feats, seed_w, seed_b, proto_t, psq_part,
                                       fsq, part_num, part_den, nullptr, nullptr);
    skm_reduce<false><<<rg, rb, 0, stream>>>(part_num, part_den, proto_t, psq_part,
                                             nullptr, probs_ws, probs_full);
    skm_pass<1><<<pg, pb, 0, stream>>>(feats, seed_w, seed_b, proto_t, psq_part,
                                       fsq, part_num, part_den, nullptr, nullptr);
    skm_reduce<false><<<rg, rb, 0, stream>>>(part_num, part_den, proto_t, psq_part,
                                             nullptr, probs_ws, probs_full);
    // iteration 3: emit logits_map + probs(=assign)
    skm_pass<2><<<pg, pb, 0, stream>>>(feats, seed_w, seed_b, proto_t, psq_part,
                                       fsq, part_num, part_den, logits_out, probs_ws);
    // final reduce (proto -> d_out) + fused bilinear x4 upsample (512-wide)
    skm_reduce<true><<<dim3(256 + 4096), rb, 0, stream>>>(part_num, part_den, proto_t, psq_part,
                                                          proto_out, probs_ws, probs_full);
}

// Round 14
// 98.867 us; speedup vs baseline: 1.2011x; 1.2011x over previous
//
#include <hip/hip_runtime.h>
#include <hip/hip_bf16.h>
#include <math.h>

#define BB   4
#define CCH  256
#define KK   8
#define NPIX 16384
#define TILE 64
#define NBLK 256           // blocks per batch = NPIX/TILE
#define TEMP_INV 1.25f     // 1/0.8
#define EPSF 1e-6f

// Falsified-levers ledger (do not retry):
//  r4/r10: bf16 global feats cache (both layouts) -- feats is L3-resident,
//          the cache only adds writeback + unpack cost.
//  r7:     hipLaunchCooperativeKernel -- not graph-capturable, aborts.
//  r9:     hand-rolled grid barrier -- ~90us/barrier (agent-scope polling).
//  r12:    8px-wide column loads (sector scatter) + cgrp store swizzle
//          (4-way conflicts) + full-row kh-split phase 2.
//  r13:    4-blocks/CU occupancy theory -- falsified (4/CU measured slower;
//          no gang-scheduling "rounds" to optimize for); bf16 cross staging
//          RMW serializes wave groups.
// This file == r11 (proven 97.9us): r6 structure + 512-wide reduce +
// MODE-1 f_sq drop + dual-chain phase 2.

__device__ __forceinline__ float bf_lo(unsigned int u) { return __uint_as_float(u << 16); }
__device__ __forceinline__ float bf_hi(unsigned int u) { return __uint_as_float(u & 0xffff0000u); }

// ---------------------------------------------------------------------------
// Pass kernel: fused distance -> softmax -> accumulate; feats read from
// global ONCE (phase 1, fp32 coalesced, lane=pixel 256B/wave); phase 2
// re-reads a bf16 LDS copy.
// MODE 0: seeds (s_load seed_w) + bias, computes f_sq.
// MODE 1: cluster iteration; f_sq DROPPED from logit (softmax-invariant).
// MODE 2: iteration + emit logits/probs (keeps f_sq for the logits output).
// Grid: BB*NBLK = 1024 blocks x 512 threads; ~52.6 KB LDS -> 3 blocks/CU.
// bf16 tile swizzle: word w of row c stored at w ^ ((c&15)<<1).
// ---------------------------------------------------------------------------
template<int MODE>
__global__ __launch_bounds__(512, 6)
void skm_pass(const float* __restrict__ feats,
              const float* __restrict__ seed_w,
              const float* __restrict__ seed_b,
              const float* __restrict__ proto_t,   // [b][256][8]
              const float* __restrict__ psq_part,  // [b][8][8]
              float* __restrict__ fsq,
              float* __restrict__ part_num,
              float* __restrict__ part_den,
              float* __restrict__ logits_out,
              float* __restrict__ probs_out)
{
    __shared__ unsigned int fb_s[CCH][32];   // 32 KB: bf16 feats tile, swizzled
    __shared__ float cross_s[8][KK][66];     // 16.5 KB
    __shared__ float w_s[KK][68];            // 2.1 KB (rows 16B-aligned)
    __shared__ float aux_s[8][TILE];         // 2 KB: fs partials (M0) / lg (M2)

    const int t   = threadIdx.x;
    const int bid = blockIdx.x;
    const int b   = bid >> 8;
    const int blk = bid & 255;
    const int n0  = blk * TILE;

    // ---- phase 1: cross[k][p]; 8 waves = 8 channel-groups of 32 ----
    const int p  = t & 63;                               // pixel (lane)
    const int g  = t >> 6;                               // wave = channel group
    const int c0 = __builtin_amdgcn_readfirstlane(g) * 32;
    const float* fcol = feats + (size_t)b * CCH * NPIX + (size_t)c0 * NPIX + n0 + p;
    const float* pt   = proto_t + (size_t)b * CCH * KK + (size_t)c0 * KK;

    float cr[KK];
    #pragma unroll
    for (int k = 0; k < KK; ++k) cr[k] = 0.f;
    float fs = 0.f;

    #pragma unroll 8
    for (int cc = 0; cc < 32; ++cc) {
        const float f = fcol[(size_t)cc * NPIX];         // coalesced 256B/wave
        if (MODE == 0) fs = fmaf(f, f, fs);
        const int c  = c0 + cc;
        const int wp = (p >> 1) ^ ((c & 15) << 1);       // swizzled word
        ((__hip_bfloat16*)fb_s)[(c << 6) + (wp << 1) + (p & 1)] = __float2bfloat16(f);
        if (MODE == 0) {
            #pragma unroll
            for (int k = 0; k < KK; ++k)
                cr[k] = fmaf(seed_w[k * CCH + c], f, cr[k]);   // uniform -> s_load
        } else {
            const float* pr = pt + cc * KK;              // uniform -> s_load x8
            #pragma unroll
            for (int k = 0; k < KK; ++k)
                cr[k] = fmaf(pr[k], f, cr[k]);
        }
    }
    #pragma unroll
    for (int k = 0; k < KK; ++k) cross_s[g][k][p] = cr[k];
    if (MODE == 0) aux_s[g][p] = fs;
    __syncthreads();

    // ---- softmax over k: thread = (pixel pp, cluster k), shuffle in octet ----
    {
        const int pp = t >> 3, k = t & 7;
        float lg = 0.f;
        #pragma unroll
        for (int gg = 0; gg < 8; ++gg) lg += cross_s[gg][k][pp];
        if (MODE == 0) {
            lg += seed_b[k];
            if (k == 0) {
                float fv = 0.f;
                #pragma unroll
                for (int gg = 0; gg < 8; ++gg) fv += aux_s[gg][pp];
                fsq[b * NPIX + n0 + pp] = fv;
            }
        } else {
            const float4 q0 = ((const float4*)psq_part)[(b * KK + k) * 2];
            const float4 q1 = ((const float4*)psq_part)[(b * KK + k) * 2 + 1];
            const float pk = ((q0.x + q0.y) + (q0.z + q0.w))
                           + ((q1.x + q1.y) + (q1.z + q1.w));
            if (MODE == 2) {
                const float fv = fsq[b * NPIX + n0 + pp];
                lg = (2.f * lg - fv - pk) * TEMP_INV;    // true -dist/TEMP (output)
            } else {
                // f_sq is constant over k -> softmax-invariant: drop it.
                lg = fmaf(2.f * TEMP_INV, lg, -TEMP_INV * pk);
            }
        }
        float m = lg;
        m = fmaxf(m, __shfl_xor(m, 1, 64));
        m = fmaxf(m, __shfl_xor(m, 2, 64));
        m = fmaxf(m, __shfl_xor(m, 4, 64));
        const float e = expf(lg - m);
        float ssum = e;
        ssum += __shfl_xor(ssum, 1, 64);
        ssum += __shfl_xor(ssum, 2, 64);
        ssum += __shfl_xor(ssum, 4, 64);
        const float wv = e / ssum;
        w_s[k][pp] = wv;
        if (MODE == 2) aux_s[k][pp] = lg;                // lg staging
    }
    __syncthreads();

    // ---- MODE 2: coalesced logits/probs writes ----
    if (MODE == 2) {
        const int k2 = t >> 6, p2 = t & 63;
        logits_out[((size_t)b * KK + k2) * NPIX + n0 + p2] = aux_s[k2][p2];
        probs_out [((size_t)b * KK + k2) * NPIX + n0 + p2] = w_s[k2][p2];
    }

    // ---- per-block denominator partials ----
    if (t < 256) {
        const int kk = t >> 5, ll = t & 31;
        float s = w_s[kk][2 * ll] + w_s[kk][2 * ll + 1];
        s += __shfl_xor(s, 16, 64);
        s += __shfl_xor(s, 8, 64);
        s += __shfl_xor(s, 4, 64);
        s += __shfl_xor(s, 2, 64);
        s += __shfl_xor(s, 1, 64);
        if (ll == 0) part_den[(b * NBLK + blk) * KK + kk] = s;
    }

    // ---- phase 2: num[k][c] from bf16 LDS tile (dual even/odd FMA chains) ----
    {
        const int c = t & 255, h = t >> 8;               // 32 px per thread
        const int s2 = (c & 15) << 1;
        const uint2* row2 = (const uint2*)fb_s[c];
        float accx[KK], accy[KK];
        #pragma unroll
        for (int k = 0; k < KK; ++k) { accx[k] = 0.f; accy[k] = 0.f; }
        #pragma unroll
        for (int j = 0; j < 8; ++j) {
            const uint2 u = row2[((16 * h + 2 * j) ^ s2) >> 1];   // b64
            const float f0 = bf_lo(u.x), f1 = bf_hi(u.x);
            const float f2 = bf_lo(u.y), f3 = bf_hi(u.y);
            const int px = 32 * h + 4 * j;
            #pragma unroll
            for (int k = 0; k < KK; ++k) {
                const float4 w4 = *(const float4*)&w_s[k][px];    // broadcast b128
                accx[k] = fmaf(f2, w4.z, fmaf(f0, w4.x, accx[k]));
                accy[k] = fmaf(f3, w4.w, fmaf(f1, w4.y, accy[k]));
            }
        }
        float (*acc_s)[KK][CCH] = (float (*)[KK][CCH])cross_s;   // reuse
        #pragma unroll
        for (int k = 0; k < KK; ++k) acc_s[h][k][c] = accx[k] + accy[k];
        __syncthreads();
        #pragma unroll
        for (int u2 = t; u2 < KK * CCH; u2 += 512) {
            const int k = u2 >> 8, c2 = u2 & 255;
            part_num[(((size_t)b * NBLK + blk) * KK + k) * CCH + c2] =
                acc_s[0][k][c2] + acc_s[1][k][c2];
        }
    }
}

// ---------------------------------------------------------------------------
// Reduce (512 threads, 16-way j-split): 256 blocks = 32 (b,k) x 8
// channel-chunks; role cq sums 256 j-partials, divides by den, writes
// proto_t (+proto_out) AND its psq_part chunk.
// FINAL=true: blocks >= 256 do the bilinear x4 upsample (512-wide).
// ---------------------------------------------------------------------------
template<bool FINAL>
__global__ __launch_bounds__(512)
void skm_reduce(const float* __restrict__ part_num,
                const float* __restrict__ part_den,
                float* __restrict__ proto_t,
                float* __restrict__ psq_part,
                float* __restrict__ proto_out,
                const float* __restrict__ probs_ws,
                float* __restrict__ probs_full)
{
    const int bid = blockIdx.x;
    if (FINAL && bid >= 256) {
        // ---- upsample role: half-pixel bilinear x4, edge clamp ----
        const int gid = (bid - 256) * 512 + threadIdx.x;   // 0..2097151
        const int jb = gid & 127;
        const int i  = (gid >> 7) & 511;
        const int bk = gid >> 16;
        const float* src = probs_ws + (size_t)bk * NPIX;
        const float y   = i * 0.25f - 0.375f;
        const float y0f = floorf(y);
        const float fy  = y - y0f;
        const int   y0  = (int)y0f;
        const int ya = min(max(y0, 0), 127);
        const int yb = min(max(y0 + 1, 0), 127);
        const int xm = max(jb - 1, 0);
        const int xp = min(jb + 1, 127);
        const float* r0 = src + ya * 128;
        const float* r1 = src + yb * 128;
        const float wy0 = 1.f - fy;
        const float am = r0[xm] * wy0 + r1[xm] * fy;
        const float ac = r0[jb] * wy0 + r1[jb] * fy;
        const float ap = r0[xp] * wy0 + r1[xp] * fy;
        float4 o;
        o.x = 0.375f * am + 0.625f * ac;
        o.y = 0.125f * am + 0.875f * ac;
        o.z = 0.875f * ac + 0.125f * ap;
        o.w = 0.625f * ac + 0.375f * ap;
        ((float4*)probs_full)[gid] = o;
        return;
    }

    const int cq = bid & 7;
    const int bk = bid >> 3;             // 0..31
    const int b = bk >> 3, k = bk & 7;
    const int t = threadIdx.x;

    __shared__ float red[16][32];
    __shared__ float den_s[4];

    // denominator: threads 0-255 read 256 block-partials, per-wave shuffle tree
    float dv = (t < 256) ? part_den[(b * NBLK + t) * KK + k] : 0.f;
    dv += __shfl_xor(dv, 32, 64);
    dv += __shfl_xor(dv, 16, 64);
    dv += __shfl_xor(dv, 8, 64);
    dv += __shfl_xor(dv, 4, 64);
    dv += __shfl_xor(dv, 2, 64);
    dv += __shfl_xor(dv, 1, 64);
    if (t < 256 && (t & 63) == 0) den_s[t >> 6] = dv;

    // numerator: 16-way j-split over this role's 32 channels
    const int jj = t >> 5, cl = t & 31;
    const int c = cq * 32 + cl;
    float s = 0.f;
    #pragma unroll 4
    for (int j = 0; j < 16; ++j)
        s += part_num[(((size_t)b * NBLK + jj * 16 + j) * KK + k) * CCH + c];
    red[jj][cl] = s;
    __syncthreads();

    if (t < 32) {
        const float den = den_s[0] + den_s[1] + den_s[2] + den_s[3] + EPSF;
        float pv = 0.f;
        #pragma unroll
        for (int j2 = 0; j2 < 16; ++j2) pv += red[j2][t];
        pv /= den;
        const int c2 = cq * 32 + t;
        proto_t[((size_t)b * CCH + c2) * KK + k] = pv;
        if (proto_out) proto_out[(b * KK + k) * CCH + c2] = pv;
        float q = pv * pv;                               // psq chunk partial
        q += __shfl_xor(q, 16, 64);
        q += __shfl_xor(q, 8, 64);
        q += __shfl_xor(q, 4, 64);
        q += __shfl_xor(q, 2, 64);
        q += __shfl_xor(q, 1, 64);
        if (t == 0) psq_part[(b * KK + k) * 8 + cq] = q;
    }
}

// ---------------------------------------------------------------------------
extern "C" void kernel_launch(void* const* d_in, const int* in_sizes, int n_in,
                              void* d_out, int out_size, void* d_ws, size_t ws_size,
                              hipStream_t stream)
{
    const float* feats  = (const float*)d_in[0];   // [4][256][16384]
    const float* seed_w = (const float*)d_in[1];   // [16][256] (first 8 rows)
    const float* seed_b = (const float*)d_in[2];   // [16]

    float* out        = (float*)d_out;
    float* probs_full = out;                        // 4*8*512*512 = 8388608
    float* proto_out  = out + 8388608;              // 4*8*256     = 8192
    float* logits_out = out + 8388608 + 8192;       // 4*8*128*128 = 524288

    float* ws       = (float*)d_ws;
    float* fsq      = ws;                           // 65536
    float* part_den = ws + 65536;                   // 4*256*8 = 8192
    float* proto_t  = part_den + 8192;              // 8192
    float* psq_part = proto_t + 8192;               // 256
    float* probs_ws = psq_part + 256;               // 524288
    float* part_num = probs_ws + 524288;            // 2097152 (~10.7 MB total)

    const dim3 pg(BB * NBLK), pb(512);
    const dim3 rg(256), rb(512);

    // seed pass + initial proto
    skm_pass<0><<<pg, pb, 0, stream>>>(feats, seed_w, seed_b, proto_t, psq_part,
                                       fsq, part_num, part_den, nullptr, nullptr);
    skm_reduce<false><<<rg, rb, 0, stream>>>(part_num, part_den, proto_t, psq_part,
                                             nullptr, probs_ws, probs_full);
    // cluster iterations 1,2
    skm_pass<1><<<pg, pb, 0, stream>>>(feats, seed_w, seed_b, proto_t, psq_part,
                                       fsq, part_num, part_den, nullptr, nullptr);
    skm_reduce<false><<<rg, rb, 0, stream>>>(part_num, part_den, proto_t, psq_part,
                                             nullptr, probs_ws, probs_full);
    skm_pass<1><<<pg, pb, 0, stream>>>(feats, seed_w, seed_b, proto_t, psq_part,
                                       fsq, part_num, part_den, nullptr, nullptr);
    skm_reduce<false><<<rg, rb, 0, stream>>>(part_num, part_den, proto_t, psq_part,
                                             nullptr, probs_ws, probs_full);
    // iteration 3: emit logits_map + probs(=assign)
    skm_pass<2><<<pg, pb, 0, stream>>>(feats, seed_w, seed_b, proto_t, psq_part,
                                       fsq, part_num, part_den, logits_out, probs_ws);
    // final reduce (proto -> d_out) + fused bilinear x4 upsample (512-wide)
    skm_reduce<true><<<dim3(256 + 4096), rb, 0, stream>>>(part_num, part_den, proto_t, psq_part,
                                                          proto_out, probs_ws, probs_full);
}